// Round 11
// baseline (441.829 us; speedup 1.0000x reference)
//
#include <hip/hip_runtime.h>

// ScaledDotProductAttention: B=2,H=16,S=2048,D=64, fp32 in/out.
// Outputs: context [B,H,S,D] then attn [B,H,S,S], concatenated in d_out.
//
// R11: barrier-free main kernel. Prep emits FRAGMENT-ORDERED bf16 images:
// for each 64x64 tile, 16B chunk (jtc, lane) holds exactly the MFMA B-frag
// data lane needs -> a wave's fragment load is one coalesced 1KB dwordx4.
// K/V are read straight from global (L2-resident: 512KB/bh, 4 bh per XCD
// under the swizzle) -- NO LDS staging, NO double buffers, NO __syncthreads.
// Only P goes through per-wave LDS (8KB total) with the proven
// lgkmcnt(0)+sched_barrier pattern. Q frags load once from global.
// Occupancy: LDS 8KB; __launch_bounds__(256,5) caps VGPR ~102 (R9 spill
// lesson: conservative). No-max softmax (exact), reg bitmask, exp2 domain.

#define S_LEN 2048
#define D_DIM 64
#define NKT 32
#define QB 64

typedef __attribute__((ext_vector_type(8))) short bf16x8;
typedef __attribute__((ext_vector_type(4))) float f32x4;
typedef __attribute__((ext_vector_type(4))) unsigned short us4;

__device__ __forceinline__ unsigned short f2bf(float f) {
    unsigned u = __builtin_bit_cast(unsigned, f);
    u += 0x7fffu + ((u >> 16) & 1u);       // RNE
    return (unsigned short)(u >> 16);
}
__device__ __forceinline__ float bf2f(unsigned short b) {
    return __builtin_bit_cast(float, (unsigned)b << 16);
}

// ---------------- prep: K,V f32 -> fragment-ordered bf16 images -------------
// Kimg tile (4096 ushorts): chunk jtc = jt*2+c, lane: K[kt*64+jt*16+lq][c*32+h*8+e]
// Vimg tile: chunk jtc = dt*2+c, lane: V[kt*64+c*32+h*8+e][dt*16+lq]
__global__ __launch_bounds__(256)
void sdpa_prep(const float* __restrict__ K, const float* __restrict__ V,
               unsigned short* __restrict__ Kimg, unsigned short* __restrict__ Vimg)
{
    const int blk = blockIdx.x;          // bh*32 + kt
    const int bh = blk >> 5, kt = blk & 31;
    const float* Kt = K + ((size_t)bh * S_LEN + kt * 64) * D_DIM;
    const float* Vt = V + ((size_t)bh * S_LEN + kt * 64) * D_DIM;
    unsigned short* Kd = Kimg + (size_t)blk * 4096;
    unsigned short* Vd = Vimg + (size_t)blk * 4096;
    const int tid  = threadIdx.x;
    const int lane = tid & 63;
    const int lq   = lane & 15;
    const int h    = lane >> 4;

    #pragma unroll
    for (int it = 0; it < 2; ++it) {
        const int jtc = (tid >> 6) + it * 4;      // 0..7
        const int jt  = jtc >> 1, c = jtc & 1;

        const float* ks = Kt + (jt * 16 + lq) * D_DIM + c * 32 + h * 8;
        us4 k0 = { f2bf(ks[0]), f2bf(ks[1]), f2bf(ks[2]), f2bf(ks[3]) };
        us4 k1 = { f2bf(ks[4]), f2bf(ks[5]), f2bf(ks[6]), f2bf(ks[7]) };
        *(us4*)(Kd + jtc * 512 + lane * 8)     = k0;
        *(us4*)(Kd + jtc * 512 + lane * 8 + 4) = k1;

        const float* vs = Vt + (size_t)(c * 32 + h * 8) * D_DIM + jt * 16 + lq;
        us4 v0 = { f2bf(vs[0 * D_DIM]), f2bf(vs[1 * D_DIM]),
                   f2bf(vs[2 * D_DIM]), f2bf(vs[3 * D_DIM]) };
        us4 v1 = { f2bf(vs[4 * D_DIM]), f2bf(vs[5 * D_DIM]),
                   f2bf(vs[6 * D_DIM]), f2bf(vs[7 * D_DIM]) };
        *(us4*)(Vd + jtc * 512 + lane * 8)     = v0;
        *(us4*)(Vd + jtc * 512 + lane * 8 + 4) = v1;
    }
}

// ------------------------------- main ---------------------------------------
__global__ __launch_bounds__(256, 5)
void sdpa_main(const float* __restrict__ Q,
               const int* __restrict__ M,
               const unsigned short* __restrict__ Kimg,
               const unsigned short* __restrict__ Vimg,
               float* __restrict__ ctx_out,
               float* __restrict__ attn_out)
{
    __shared__ __align__(16) unsigned short sP[4][1024];   // 8KB total

    const int tid  = threadIdx.x;
    const int lane = tid & 63;
    const int w    = tid >> 6;
    const int lq   = lane & 15;
    const int h    = lane >> 4;
    const int l7   = lq & 7;

    int b   = blockIdx.x;
    int swz = (b & 7) * 128 + (b >> 3);
    int bh  = swz >> 5, qt = swz & 31;
    const int q0 = qt * QB;

    const float* Qh = Q + ((size_t)bh * S_LEN + q0) * D_DIM;
    const int*   Mh = M + (size_t)bh * S_LEN * S_LEN;
    const unsigned short* KhF = Kimg + (size_t)bh * NKT * 4096;
    const unsigned short* VhF = Vimg + (size_t)bh * NKT * 4096;
    float* Ah = attn_out + (size_t)bh * S_LEN * S_LEN;
    float* Ch = ctx_out  + (size_t)bh * S_LEN * D_DIM;

    const int* Mb = Mh + (size_t)(q0 + w * 16 + h * 4) * S_LEN + lq;

    // ---- Q fragments straight from global (one-time), scaled to log2 domain
    const float SC = 0.18033688011112042f;   // 0.125 * log2(e)
    const float* Qrow = Qh + (w * 16 + lq) * D_DIM;
    bf16x8 aq0, aq1;
    #pragma unroll
    for (int e = 0; e < 8; ++e) {
        aq0[e] = (short)f2bf(Qrow[h * 8 + e] * SC);
        aq1[e] = (short)f2bf(Qrow[32 + h * 8 + e] * SC);
    }

    // ================= pass 1: row sum(exp2) + reg bitmask ==================
    float lsum[4];
    unsigned bits[4][4];
    #pragma unroll
    for (int r = 0; r < 4; ++r) {
        lsum[r] = 0.f;
        #pragma unroll
        for (int jt = 0; jt < 4; ++jt) bits[jt][r] = 0u;
    }

    for (int kt = 0; kt < NKT; ++kt) {
        const unsigned short* kb = KhF + kt * 4096;

        int mm[4][4];
        #pragma unroll
        for (int jt = 0; jt < 4; ++jt)
            #pragma unroll
            for (int r = 0; r < 4; ++r)
                mm[jt][r] = Mb[(size_t)r * S_LEN + kt * 64 + jt * 16];

        f32x4 acc[4];
        #pragma unroll
        for (int jt = 0; jt < 4; ++jt) {
            bf16x8 b0 = *(const bf16x8*)(kb + (jt * 2 + 0) * 512 + lane * 8);
            bf16x8 b1 = *(const bf16x8*)(kb + (jt * 2 + 1) * 512 + lane * 8);
            acc[jt] = (f32x4){0.f, 0.f, 0.f, 0.f};
            acc[jt] = __builtin_amdgcn_mfma_f32_16x16x32_bf16(aq0, b0, acc[jt], 0, 0, 0);
            acc[jt] = __builtin_amdgcn_mfma_f32_16x16x32_bf16(aq1, b1, acc[jt], 0, 0, 0);
        }

        #pragma unroll
        for (int r = 0; r < 4; ++r) {
            float e4[4];
            #pragma unroll
            for (int jt = 0; jt < 4; ++jt) {
                unsigned ms = mm[jt][r] ? 1u : 0u;
                bits[jt][r] |= ms << kt;
                float ev = exp2f(acc[jt][r]);
                e4[jt] = ms ? 0.f : ev;
            }
            lsum[r] += (e4[0] + e4[1]) + (e4[2] + e4[3]);
        }
    }

    // add-only butterfly; total lands in all 16 lanes
    float myIL[4];
    #pragma unroll
    for (int r = 0; r < 4; ++r) {
        float li = lsum[r];
        #pragma unroll
        for (int off = 1; off < 16; off <<= 1)
            li += __shfl_xor(li, off);
        myIL[r] = (li > 0.f) ? (1.f / li) : 0.f;
    }

    // ================= pass 2: attn write + PV ==============================
    f32x4 ctxa[4];
    #pragma unroll
    for (int dt = 0; dt < 4; ++dt) ctxa[dt] = (f32x4){0.f, 0.f, 0.f, 0.f};

    unsigned short* const sPw = sP[w];
    float* const Abase = Ah + (size_t)(q0 + w * 16) * S_LEN;

    for (int kt = 0; kt < NKT; ++kt) {
        const unsigned short* kb = KhF + kt * 4096;

        f32x4 acc[4];
        #pragma unroll
        for (int jt = 0; jt < 4; ++jt) {
            bf16x8 b0 = *(const bf16x8*)(kb + (jt * 2 + 0) * 512 + lane * 8);
            bf16x8 b1 = *(const bf16x8*)(kb + (jt * 2 + 1) * 512 + lane * 8);
            acc[jt] = (f32x4){0.f, 0.f, 0.f, 0.f};
            acc[jt] = __builtin_amdgcn_mfma_f32_16x16x32_bf16(aq0, b0, acc[jt], 0, 0, 0);
            acc[jt] = __builtin_amdgcn_mfma_f32_16x16x32_bf16(aq1, b1, acc[jt], 0, 0, 0);
        }

        // P -> per-wave swizzled LDS tile (bf16)
        #pragma unroll
        for (int jt = 0; jt < 4; ++jt)
            #pragma unroll
            for (int r = 0; r < 4; ++r) {
                bool msk = (bits[jt][r] >> kt) & 1u;
                float p = exp2f(acc[jt][r]) * myIL[r];
                p = msk ? 0.f : p;
                int row = h * 4 + r;
                sPw[row * 64 + ((((jt << 1) | (lq >> 3)) ^ (row & 7)) << 3) + l7] = f2bf(p);
            }
        asm volatile("s_waitcnt lgkmcnt(0)" ::: "memory");
        __builtin_amdgcn_sched_barrier(0);

        // coalesced attn write from sPw
        float* Aw = Abase + kt * 64;
        #pragma unroll
        for (int it = 0; it < 4; ++it) {
            int row = it * 4 + h;
            us4 pb = *(const us4*)(&sPw[row * 64 + (((lq >> 1) ^ (row & 7)) << 3) + (lq & 1) * 4]);
            float4 pf = make_float4(bf2f(pb.x), bf2f(pb.y), bf2f(pb.z), bf2f(pb.w));
            *(float4*)(Aw + (size_t)row * S_LEN + lq * 4) = pf;
        }

        // PV from fragment-ordered V image (global, L2-resident)
        bf16x8 pa0 = *(const bf16x8*)(&sPw[lq * 64 + ((h ^ l7) << 3)]);
        bf16x8 pa1 = *(const bf16x8*)(&sPw[lq * 64 + (((4 + h) ^ l7) << 3)]);
        const unsigned short* vb = VhF + kt * 4096;
        #pragma unroll
        for (int dt = 0; dt < 4; ++dt) {
            bf16x8 v0 = *(const bf16x8*)(vb + (dt * 2 + 0) * 512 + lane * 8);
            bf16x8 v1 = *(const bf16x8*)(vb + (dt * 2 + 1) * 512 + lane * 8);
            ctxa[dt] = __builtin_amdgcn_mfma_f32_16x16x32_bf16(pa0, v0, ctxa[dt], 0, 0, 0);
            ctxa[dt] = __builtin_amdgcn_mfma_f32_16x16x32_bf16(pa1, v1, ctxa[dt], 0, 0, 0);
        }
    }

    float* Crow = Ch + (size_t)(q0 + w * 16 + h * 4) * D_DIM;
    #pragma unroll
    for (int dt = 0; dt < 4; ++dt)
        #pragma unroll
        for (int r = 0; r < 4; ++r)
            Crow[(size_t)r * D_DIM + dt * 16 + lq] = ctxa[dt][r];
}

extern "C" void kernel_launch(void* const* d_in, const int* in_sizes, int n_in,
                              void* d_out, int out_size, void* d_ws, size_t ws_size,
                              hipStream_t stream)
{
    const float* Q = (const float*)d_in[0];
    const float* K = (const float*)d_in[1];
    const float* V = (const float*)d_in[2];
    const int*   M = (const int*)d_in[3];

    float* ctx  = (float*)d_out;
    float* attn = ctx + (size_t)2 * 16 * S_LEN * D_DIM;

    const size_t imgElems = (size_t)32 * NKT * 4096;
    if (ws_size < 2 * imgElems * sizeof(unsigned short)) return; // need 16 MB
    unsigned short* Kimg = (unsigned short*)d_ws;
    unsigned short* Vimg = Kimg + imgElems;

    sdpa_prep<<<dim3(1024), 256, 0, stream>>>(K, V, Kimg, Vimg);
    sdpa_main<<<dim3(1024), 256, 0, stream>>>(Q, M, Kimg, Vimg, ctx, attn);
}

// Round 12
// 361.560 us; speedup vs baseline: 1.2220x; 1.2220x over previous
//
#include <hip/hip_runtime.h>

// ScaledDotProductAttention: B=2,H=16,S=2048,D=64, fp32 in/out.
// Outputs: context [B,H,S,D] then attn [B,H,S,S], concatenated in d_out.
//
// R12: R10 pass 1 (verbatim, 2-tiles-per-barrier, quad-K) + pass 2 upgraded
// to the same 2-tiles-per-barrier scheme: K quad-buffer via global_load_lds
// (32KB) + per-wave P (8KB) = 40960B LDS; V read DIRECT from a
// fragment-ordered bf16 image (R11 layout) -- V's consumer (PV) sits ~1us
// behind the step top (QK^T+softmax+attn-write), so L2 latency is covered.
// R11 lessons applied: launch_bounds(256,4) not (256,5) (VGPR 48 strangle),
// and only V is direct (K feeds the first MFMA -> stays LDS-staged).
// No-max softmax (exact), reg bitmask, exp2 domain, XCD swizzle.

#define S_LEN 2048
#define D_DIM 64
#define NKT 32
#define QB 64

typedef __attribute__((ext_vector_type(8))) short bf16x8;
typedef __attribute__((ext_vector_type(4))) float f32x4;
typedef __attribute__((ext_vector_type(4))) unsigned short us4;

__device__ __forceinline__ unsigned short f2bf(float f) {
    unsigned u = __builtin_bit_cast(unsigned, f);
    u += 0x7fffu + ((u >> 16) & 1u);       // RNE
    return (unsigned short)(u >> 16);
}
__device__ __forceinline__ float bf2f(unsigned short b) {
    return __builtin_bit_cast(float, (unsigned)b << 16);
}

typedef const __attribute__((address_space(1))) void cg_void;
typedef __attribute__((address_space(3))) void lds_void;
__device__ __forceinline__ void gload16(const void* g, void* l) {
    __builtin_amdgcn_global_load_lds((cg_void*)g, (lds_void*)l, 16, 0, 0);
}

// -------- prep: K -> LDS-swizzled tiles; V -> fragment-ordered tiles --------
// Kimg tile: byte row*128 + ((c16 ^ (row&7))<<4) + sub (R10 format, for
//            gload_lds staging + swizzled ds_read).
// Vimg tile (4096 ushorts): chunk jtc=dt*2+c, lane: V[c*32+h*8+e][dt*16+lq]
//            (R11 format: one dwordx4 per lane = whole B-fragment).
__global__ __launch_bounds__(256)
void sdpa_prep(const float* __restrict__ K, const float* __restrict__ V,
               unsigned short* __restrict__ Kimg, unsigned short* __restrict__ Vimg)
{
    const int blk = blockIdx.x;          // bh*32 + kt
    const int bh = blk >> 5, kt = blk & 31;
    const float* Kt = K + ((size_t)bh * S_LEN + kt * 64) * D_DIM;
    const float* Vt = V + ((size_t)bh * S_LEN + kt * 64) * D_DIM;
    unsigned char*  Kd = (unsigned char*)(Kimg + (size_t)blk * 4096);
    unsigned short* Vd = Vimg + (size_t)blk * 4096;
    const int tid  = threadIdx.x;
    const int lane = tid & 63;
    const int lq   = lane & 15;
    const int h    = lane >> 4;

    // K (R10 swizzled-row format)
    {
        const int srow = tid >> 4, c4 = tid & 15;
        #pragma unroll
        for (int i = 0; i < 4; ++i) {
            int row = srow + i * 16;
            float4 v = *(const float4*)(Kt + (size_t)row * D_DIM + c4 * 4);
            us4 b = { f2bf(v.x), f2bf(v.y), f2bf(v.z), f2bf(v.w) };
            *(us4*)(Kd + row * 128 + (((c4 >> 1) ^ (row & 7)) << 4) + (c4 & 1) * 8) = b;
        }
    }
    // V (R11 fragment-ordered format)
    #pragma unroll
    for (int it = 0; it < 2; ++it) {
        const int jtc = (tid >> 6) + it * 4;      // 0..7
        const int dt  = jtc >> 1, c = jtc & 1;
        const float* vs = Vt + (size_t)(c * 32 + h * 8) * D_DIM + dt * 16 + lq;
        us4 v0 = { f2bf(vs[0 * D_DIM]), f2bf(vs[1 * D_DIM]),
                   f2bf(vs[2 * D_DIM]), f2bf(vs[3 * D_DIM]) };
        us4 v1 = { f2bf(vs[4 * D_DIM]), f2bf(vs[5 * D_DIM]),
                   f2bf(vs[6 * D_DIM]), f2bf(vs[7 * D_DIM]) };
        *(us4*)(Vd + jtc * 512 + lane * 8)     = v0;
        *(us4*)(Vd + jtc * 512 + lane * 8 + 4) = v1;
    }
}

// ------------------------------- main ---------------------------------------
__global__ __launch_bounds__(256, 4)
void sdpa_main(const float* __restrict__ Q,
               const int* __restrict__ M,
               const unsigned short* __restrict__ Kimg,
               const unsigned short* __restrict__ Vimg,
               float* __restrict__ ctx_out,
               float* __restrict__ attn_out)
{
    __shared__ __align__(16) unsigned char smem[40960];
    // both passes: K quad-buffer [0..32K) as 2 pairs.
    // pass 1: Q swizzled [32K..40K).  pass 2: per-wave P [32K..40K).
    unsigned short* const sPB = (unsigned short*)(smem + 32768);
    unsigned short* const sQl = (unsigned short*)(smem + 32768);

    const int tid  = threadIdx.x;
    const int lane = tid & 63;
    const int w    = tid >> 6;
    const int lq   = lane & 15;
    const int h    = lane >> 4;
    const int l7   = lq & 7;

    int b   = blockIdx.x;
    int swz = (b & 7) * 128 + (b >> 3);
    int bh  = swz >> 5, qt = swz & 31;
    const int q0 = qt * QB;

    const float* Qh = Q + ((size_t)bh * S_LEN + q0) * D_DIM;
    const int*   Mh = M + (size_t)bh * S_LEN * S_LEN;
    const unsigned short* Kh = Kimg + (size_t)bh * NKT * 4096;
    const unsigned short* Vh = Vimg + (size_t)bh * NKT * 4096;
    float* Ah = attn_out + (size_t)bh * S_LEN * S_LEN;
    float* Ch = ctx_out  + (size_t)bh * S_LEN * D_DIM;

    // frag chunk offsets (ushort units); row&7 == lq&7 for rows jt*16+lq
    const int kf0 = ((h)     ^ l7) << 3;
    const int kf1 = ((4 + h) ^ l7) << 3;

    const int* Mb = Mh + (size_t)(q0 + w * 16 + h * 4) * S_LEN + lq;

    unsigned bits[4][4];
    #pragma unroll
    for (int jt = 0; jt < 4; ++jt)
        #pragma unroll
        for (int r = 0; r < 4; ++r)
            bits[jt][r] = 0u;

    // ---- prologue: issue K(0),K(1); pack mask tiles 0,1; stage Q ----------
    #pragma unroll
    for (int tt = 0; tt < 2; ++tt)
        #pragma unroll
        for (int i = 0; i < 2; ++i)
            gload16((const unsigned char*)(Kh + (size_t)tt * 4096) + w * 2048 + i * 1024 + lane * 16,
                    smem + tt * 8192 + w * 2048 + i * 1024);
    __builtin_amdgcn_sched_barrier(0);

    #pragma unroll
    for (int tt = 0; tt < 2; ++tt)
        #pragma unroll
        for (int jt = 0; jt < 4; ++jt)
            #pragma unroll
            for (int r = 0; r < 4; ++r) {
                int m = Mb[(size_t)r * S_LEN + tt * 64 + jt * 16];
                bits[jt][r] |= (m ? 1u : 0u) << tt;
            }

    const float SC = 0.18033688011112042f;   // 0.125 * log2(e)
    {
        const int srow = tid >> 4, c4 = tid & 15;
        #pragma unroll
        for (int i = 0; i < 4; ++i) {
            int row = srow + i * 16;
            float4 v = *(const float4*)(Qh + (size_t)row * D_DIM + c4 * 4);
            us4 bq = { f2bf(v.x * SC), f2bf(v.y * SC), f2bf(v.z * SC), f2bf(v.w * SC) };
            *(us4*)((unsigned char*)sQl + row * 128 + (((c4 >> 1) ^ (row & 7)) << 4) + (c4 & 1) * 8) = bq;
        }
    }
    __syncthreads();   // Q staged, K(0),K(1) resident

    bf16x8 aq0 = *(const bf16x8*)(&sQl[(w * 16 + lq) * 64 + kf0]);
    bf16x8 aq1 = *(const bf16x8*)(&sQl[(w * 16 + lq) * 64 + kf1]);

    // ================= pass 1: 16 steps x 2 tiles (R10 verbatim) ============
    float lsum[4];
    #pragma unroll
    for (int r = 0; r < 4; ++r) lsum[r] = 0.f;

    for (int s = 0; s < 16; ++s) {
        const int kt0 = 2 * s;
        unsigned char* curp = smem + (s & 1) * 16384;
        unsigned char* nxtp = smem + ((s & 1) ^ 1) * 16384;
        const bool more = (s + 1 < 16);

        if (more) {
            #pragma unroll
            for (int tt = 0; tt < 2; ++tt)
                #pragma unroll
                for (int i = 0; i < 2; ++i)
                    gload16((const unsigned char*)(Kh + (size_t)(kt0 + 2 + tt) * 4096) + w * 2048 + i * 1024 + lane * 16,
                            nxtp + tt * 8192 + w * 2048 + i * 1024);
        }
        __builtin_amdgcn_sched_barrier(0);

        int mn[2][4][4];
        if (more) {
            #pragma unroll
            for (int tt = 0; tt < 2; ++tt)
                #pragma unroll
                for (int jt = 0; jt < 4; ++jt)
                    #pragma unroll
                    for (int r = 0; r < 4; ++r)
                        mn[tt][jt][r] = Mb[(size_t)r * S_LEN + (kt0 + 2 + tt) * 64 + jt * 16];
        }

        #pragma unroll
        for (int tt = 0; tt < 2; ++tt) {
            const unsigned short* kbuf = (const unsigned short*)(curp + tt * 8192);
            f32x4 acc[4];
            #pragma unroll
            for (int jt = 0; jt < 4; ++jt) {
                acc[jt] = (f32x4){0.f, 0.f, 0.f, 0.f};
                const unsigned short* kb = kbuf + (jt * 16 + lq) * 64;
                bf16x8 b0 = *(const bf16x8*)(kb + kf0);
                bf16x8 b1 = *(const bf16x8*)(kb + kf1);
                acc[jt] = __builtin_amdgcn_mfma_f32_16x16x32_bf16(aq0, b0, acc[jt], 0, 0, 0);
                acc[jt] = __builtin_amdgcn_mfma_f32_16x16x32_bf16(aq1, b1, acc[jt], 0, 0, 0);
            }
            #pragma unroll
            for (int r = 0; r < 4; ++r) {
                float e[4];
                #pragma unroll
                for (int jt = 0; jt < 4; ++jt) {
                    unsigned msk = (bits[jt][r] >> (kt0 + tt)) & 1u;
                    float ev = exp2f(acc[jt][r]);
                    e[jt] = msk ? 0.f : ev;
                }
                lsum[r] += (e[0] + e[1]) + (e[2] + e[3]);
            }
        }

        if (more) {
            #pragma unroll
            for (int tt = 0; tt < 2; ++tt)
                #pragma unroll
                for (int jt = 0; jt < 4; ++jt)
                    #pragma unroll
                    for (int r = 0; r < 4; ++r)
                        bits[jt][r] |= (mn[tt][jt][r] ? 1u : 0u) << (kt0 + 2 + tt);
        }
        __syncthreads();
    }

    // add-only butterfly; full 16-wide xor leaves the total in ALL lanes
    float myIL[4];
    #pragma unroll
    for (int r = 0; r < 4; ++r) {
        float li = lsum[r];
        #pragma unroll
        for (int off = 1; off < 16; off <<= 1)
            li += __shfl_xor(li, off);
        myIL[r] = (li > 0.f) ? (1.f / li) : 0.f;
    }

    // ---- pass-2 prologue: issue K(0),K(1) into pair 0 ----
    #pragma unroll
    for (int tt = 0; tt < 2; ++tt)
        #pragma unroll
        for (int i = 0; i < 2; ++i)
            gload16((const unsigned char*)(Kh + (size_t)tt * 4096) + w * 2048 + i * 1024 + lane * 16,
                    smem + tt * 8192 + w * 2048 + i * 1024);
    __syncthreads();

    // ================= pass 2: 16 steps x 2 tiles ===========================
    f32x4 ctxa[4];
    #pragma unroll
    for (int dt = 0; dt < 4; ++dt) ctxa[dt] = (f32x4){0.f, 0.f, 0.f, 0.f};

    unsigned short* const sPw = sPB + w * 1024;
    float* const Abase = Ah + (size_t)(q0 + w * 16) * S_LEN;

    for (int s = 0; s < 16; ++s) {
        const int kt0 = 2 * s;
        unsigned char* curp = smem + (s & 1) * 16384;
        unsigned char* nxtp = smem + ((s & 1) ^ 1) * 16384;
        const bool more = (s + 1 < 16);

        if (more) {
            #pragma unroll
            for (int tt = 0; tt < 2; ++tt)
                #pragma unroll
                for (int i = 0; i < 2; ++i)
                    gload16((const unsigned char*)(Kh + (size_t)(kt0 + 2 + tt) * 4096) + w * 2048 + i * 1024 + lane * 16,
                            nxtp + tt * 8192 + w * 2048 + i * 1024);
        }
        __builtin_amdgcn_sched_barrier(0);

        #pragma unroll
        for (int tt = 0; tt < 2; ++tt) {
            const int kt = kt0 + tt;
            const unsigned short* kbuf = (const unsigned short*)(curp + tt * 8192);

            f32x4 acc[4];
            #pragma unroll
            for (int jt = 0; jt < 4; ++jt) {
                acc[jt] = (f32x4){0.f, 0.f, 0.f, 0.f};
                const unsigned short* kb = kbuf + (jt * 16 + lq) * 64;
                bf16x8 b0 = *(const bf16x8*)(kb + kf0);
                bf16x8 b1 = *(const bf16x8*)(kb + kf1);
                acc[jt] = __builtin_amdgcn_mfma_f32_16x16x32_bf16(aq0, b0, acc[jt], 0, 0, 0);
                acc[jt] = __builtin_amdgcn_mfma_f32_16x16x32_bf16(aq1, b1, acc[jt], 0, 0, 0);
            }

            // wave-local: prior ds_reads of sPw (tt=0 attn/pa) done before overwrite
            asm volatile("s_waitcnt lgkmcnt(0)" ::: "memory");

            // P -> per-wave swizzled LDS tile (bf16)
            #pragma unroll
            for (int jt = 0; jt < 4; ++jt)
                #pragma unroll
                for (int r = 0; r < 4; ++r) {
                    bool msk = (bits[jt][r] >> kt) & 1u;
                    float p = exp2f(acc[jt][r]) * myIL[r];
                    p = msk ? 0.f : p;
                    int row = h * 4 + r;
                    sPw[row * 64 + ((((jt << 1) | (lq >> 3)) ^ (row & 7)) << 3) + l7] = f2bf(p);
                }
            asm volatile("s_waitcnt lgkmcnt(0)" ::: "memory");
            __builtin_amdgcn_sched_barrier(0);

            // coalesced attn write from sPw
            float* Aw = Abase + kt * 64;
            #pragma unroll
            for (int it = 0; it < 4; ++it) {
                int row = it * 4 + h;
                us4 pb = *(const us4*)(&sPw[row * 64 + (((lq >> 1) ^ (row & 7)) << 3) + (lq & 1) * 4]);
                float4 pf = make_float4(bf2f(pb.x), bf2f(pb.y), bf2f(pb.z), bf2f(pb.w));
                *(float4*)(Aw + (size_t)row * S_LEN + lq * 4) = pf;
            }

            // PV: P from LDS, V direct from fragment-ordered image (L2)
            bf16x8 pa0 = *(const bf16x8*)(&sPw[lq * 64 + ((h ^ l7) << 3)]);
            bf16x8 pa1 = *(const bf16x8*)(&sPw[lq * 64 + (((4 + h) ^ l7) << 3)]);
            const unsigned short* vb = Vh + (size_t)kt * 4096;
            #pragma unroll
            for (int dt = 0; dt < 4; ++dt) {
                bf16x8 v0 = *(const bf16x8*)(vb + (dt * 2 + 0) * 512 + lane * 8);
                bf16x8 v1 = *(const bf16x8*)(vb + (dt * 2 + 1) * 512 + lane * 8);
                ctxa[dt] = __builtin_amdgcn_mfma_f32_16x16x32_bf16(pa0, v0, ctxa[dt], 0, 0, 0);
                ctxa[dt] = __builtin_amdgcn_mfma_f32_16x16x32_bf16(pa1, v1, ctxa[dt], 0, 0, 0);
            }
        }
        __syncthreads();
    }

    float* Crow = Ch + (size_t)(q0 + w * 16 + h * 4) * D_DIM;
    #pragma unroll
    for (int dt = 0; dt < 4; ++dt)
        #pragma unroll
        for (int r = 0; r < 4; ++r)
            Crow[(size_t)r * D_DIM + dt * 16 + lq] = ctxa[dt][r];
}

extern "C" void kernel_launch(void* const* d_in, const int* in_sizes, int n_in,
                              void* d_out, int out_size, void* d_ws, size_t ws_size,
                              hipStream_t stream)
{
    const float* Q = (const float*)d_in[0];
    const float* K = (const float*)d_in[1];
    const float* V = (const float*)d_in[2];
    const int*   M = (const int*)d_in[3];

    float* ctx  = (float*)d_out;
    float* attn = ctx + (size_t)2 * 16 * S_LEN * D_DIM;

    const size_t imgElems = (size_t)32 * NKT * 4096;
    if (ws_size < 2 * imgElems * sizeof(unsigned short)) return; // need 16 MB
    unsigned short* Kimg = (unsigned short*)d_ws;
    unsigned short* Vimg = Kimg + imgElems;

    sdpa_prep<<<dim3(1024), 256, 0, stream>>>(K, V, Kimg, Vimg);
    sdpa_main<<<dim3(1024), 256, 0, stream>>>(Q, M, Kimg, Vimg, ctx, attn);
}

// Round 13
// 299.763 us; speedup vs baseline: 1.4739x; 1.2062x over previous
//
#include <hip/hip_runtime.h>

// ScaledDotProductAttention: B=2,H=16,S=2048,D=64, fp32 in/out.
// Outputs: context [B,H,S,D] then attn [B,H,S,S], concatenated in d_out.
//
// R13: R10's per-wave code at QB=128 geometry. 512 threads / 8 waves /
// block, grid 512 (= exactly 2 blocks/CU, 16 waves/CU like R10).
// Pass 1: K quad-buffer (2 pairs x 16KB), 16 steps, 1 barrier each.
// Pass 2: K quad + V quad (V LDS-staged again -- R12's V-direct regressed:
// sched_barrier fences pin V loads to their PV use -> exposed latency),
// 16 steps x 2 tiles, 1 barrier each. P per-wave LDS (16KB).
// LDS = 32K(K) + 32K(V) + 16K(P) = 81920B = exactly 160KB/2.
// Q staged swizzled in the V region (dead until pass 2).
// Per-CU barrier events: R10 192 -> 64. K/V staging bytes per CU halved.
// No-max softmax (exact), reg bitmask, exp2 domain, XCD swizzle (512%8==0).

#define S_LEN 2048
#define D_DIM 64
#define NKT 32
#define QB 128

typedef __attribute__((ext_vector_type(8))) short bf16x8;
typedef __attribute__((ext_vector_type(4))) float f32x4;
typedef __attribute__((ext_vector_type(4))) unsigned short us4;

__device__ __forceinline__ unsigned short f2bf(float f) {
    unsigned u = __builtin_bit_cast(unsigned, f);
    u += 0x7fffu + ((u >> 16) & 1u);       // RNE
    return (unsigned short)(u >> 16);
}
__device__ __forceinline__ float bf2f(unsigned short b) {
    return __builtin_bit_cast(float, (unsigned)b << 16);
}

typedef const __attribute__((address_space(1))) void cg_void;
typedef __attribute__((address_space(3))) void lds_void;
__device__ __forceinline__ void gload16(const void* g, void* l) {
    __builtin_amdgcn_global_load_lds((cg_void*)g, (lds_void*)l, 16, 0, 0);
}

// ---------------- prep: K,V f32 -> swizzled bf16 tiles in ws (R10 format) ---
__global__ __launch_bounds__(256)
void sdpa_prep(const float* __restrict__ K, const float* __restrict__ V,
               unsigned short* __restrict__ Kimg, unsigned short* __restrict__ Vimg)
{
    const int blk = blockIdx.x;          // bh*32 + kt
    const int bh = blk >> 5, kt = blk & 31;
    const float* Kt = K + ((size_t)bh * S_LEN + kt * 64) * D_DIM;
    const float* Vt = V + ((size_t)bh * S_LEN + kt * 64) * D_DIM;
    unsigned char* Kd = (unsigned char*)(Kimg + (size_t)blk * 4096);
    unsigned char* Vd = (unsigned char*)(Vimg + (size_t)blk * 4096);
    const int tid = threadIdx.x;

    {
        const int srow = tid >> 4, c4 = tid & 15;
        #pragma unroll
        for (int i = 0; i < 4; ++i) {
            int row = srow + i * 16;
            float4 v = *(const float4*)(Kt + (size_t)row * D_DIM + c4 * 4);
            us4 b = { f2bf(v.x), f2bf(v.y), f2bf(v.z), f2bf(v.w) };
            *(us4*)(Kd + row * 128 + (((c4 >> 1) ^ (row & 7)) << 4) + (c4 & 1) * 8) = b;
        }
    }
    {
        const int d = tid & 63, kg = tid >> 6;
        #pragma unroll
        for (int kk = 0; kk < 4; ++kk) {
            int k4 = kg * 4 + kk;
            int k0 = k4 * 4;
            float v0 = Vt[(size_t)(k0 + 0) * D_DIM + d];
            float v1 = Vt[(size_t)(k0 + 1) * D_DIM + d];
            float v2 = Vt[(size_t)(k0 + 2) * D_DIM + d];
            float v3 = Vt[(size_t)(k0 + 3) * D_DIM + d];
            us4 b = { f2bf(v0), f2bf(v1), f2bf(v2), f2bf(v3) };
            *(us4*)(Vd + d * 128 + (((k4 >> 1) ^ (d & 7)) << 4) + (k4 & 1) * 8) = b;
        }
    }
}

// ------------------------------- main ---------------------------------------
__global__ __launch_bounds__(512, 4)
void sdpa_main(const float* __restrict__ Q,
               const int* __restrict__ M,
               const unsigned short* __restrict__ Kimg,
               const unsigned short* __restrict__ Vimg,
               float* __restrict__ ctx_out,
               float* __restrict__ attn_out)
{
    __shared__ __align__(16) unsigned char smem[81920];
    // K quad [0..32K): pair p at p*16K, tile tt at +tt*8K
    // V quad [32K..64K): same layout (pass 2); Q swizzled overlay [32K..48K)
    // P [64K..80K): per-wave 2KB
    unsigned short* const sPB = (unsigned short*)(smem + 65536);
    unsigned short* const sQl = (unsigned short*)(smem + 32768);

    const int tid  = threadIdx.x;
    const int lane = tid & 63;
    const int w    = tid >> 6;      // 0..7
    const int lq   = lane & 15;
    const int h    = lane >> 4;
    const int l7   = lq & 7;

    int b   = blockIdx.x;
    int swz = (b & 7) * 64 + (b >> 3);    // 512 blocks, bijective
    int bh  = swz >> 4, qt = swz & 15;
    const int q0 = qt * QB;

    const float* Qh = Q + ((size_t)bh * S_LEN + q0) * D_DIM;
    const int*   Mh = M + (size_t)bh * S_LEN * S_LEN;
    const unsigned short* Kh = Kimg + (size_t)bh * NKT * 4096;
    const unsigned short* Vh = Vimg + (size_t)bh * NKT * 4096;
    float* Ah = attn_out + (size_t)bh * S_LEN * S_LEN;
    float* Ch = ctx_out  + (size_t)bh * S_LEN * D_DIM;

    // frag chunk offsets (ushort units); row&7 == lq&7 for rows jt*16+lq
    const int kf0 = ((h)     ^ l7) << 3;
    const int kf1 = ((4 + h) ^ l7) << 3;

    const int* Mb = Mh + (size_t)(q0 + w * 16 + h * 4) * S_LEN + lq;

    unsigned bits[4][4];
    #pragma unroll
    for (int jt = 0; jt < 4; ++jt)
        #pragma unroll
        for (int r = 0; r < 4; ++r)
            bits[jt][r] = 0u;

    // ---- prologue: issue K(0),K(1); pack mask tiles 0,1; stage Q ----------
    #pragma unroll
    for (int tt = 0; tt < 2; ++tt)
        gload16((const unsigned char*)(Kh + (size_t)tt * 4096) + tid * 16,
                smem + tt * 8192 + tid * 16);
    __builtin_amdgcn_sched_barrier(0);

    #pragma unroll
    for (int tt = 0; tt < 2; ++tt)
        #pragma unroll
        for (int jt = 0; jt < 4; ++jt)
            #pragma unroll
            for (int r = 0; r < 4; ++r) {
                int m = Mb[(size_t)r * S_LEN + tt * 64 + jt * 16];
                bits[jt][r] |= (m ? 1u : 0u) << tt;
            }

    const float SC = 0.18033688011112042f;   // 0.125 * log2(e)
    {
        #pragma unroll
        for (int i = 0; i < 4; ++i) {
            int f4 = tid + i * 512;
            int row = f4 >> 4, c4 = f4 & 15;    // rows 0..127
            float4 v = *(const float4*)(Qh + (size_t)row * D_DIM + c4 * 4);
            us4 bq = { f2bf(v.x * SC), f2bf(v.y * SC), f2bf(v.z * SC), f2bf(v.w * SC) };
            *(us4*)((unsigned char*)sQl + row * 128 + (((c4 >> 1) ^ (row & 7)) << 4) + (c4 & 1) * 8) = bq;
        }
    }
    __syncthreads();   // Q staged, K(0),K(1) resident

    bf16x8 aq0 = *(const bf16x8*)(&sQl[(w * 16 + lq) * 64 + kf0]);
    bf16x8 aq1 = *(const bf16x8*)(&sQl[(w * 16 + lq) * 64 + kf1]);

    // ================= pass 1: 16 steps x 2 tiles ===========================
    float lsum[4];
    #pragma unroll
    for (int r = 0; r < 4; ++r) lsum[r] = 0.f;

    for (int s = 0; s < 16; ++s) {
        const int kt0 = 2 * s;
        unsigned char* curp = smem + (s & 1) * 16384;
        unsigned char* nxtp = smem + ((s & 1) ^ 1) * 16384;
        const bool more = (s + 1 < 16);

        if (more) {
            #pragma unroll
            for (int tt = 0; tt < 2; ++tt)
                gload16((const unsigned char*)(Kh + (size_t)(kt0 + 2 + tt) * 4096) + tid * 16,
                        nxtp + tt * 8192 + tid * 16);
        }
        __builtin_amdgcn_sched_barrier(0);

        int mn[2][4][4];
        if (more) {
            #pragma unroll
            for (int tt = 0; tt < 2; ++tt)
                #pragma unroll
                for (int jt = 0; jt < 4; ++jt)
                    #pragma unroll
                    for (int r = 0; r < 4; ++r)
                        mn[tt][jt][r] = Mb[(size_t)r * S_LEN + (kt0 + 2 + tt) * 64 + jt * 16];
        }

        #pragma unroll
        for (int tt = 0; tt < 2; ++tt) {
            const unsigned short* kbuf = (const unsigned short*)(curp + tt * 8192);
            f32x4 acc[4];
            #pragma unroll
            for (int jt = 0; jt < 4; ++jt) {
                acc[jt] = (f32x4){0.f, 0.f, 0.f, 0.f};
                const unsigned short* kb = kbuf + (jt * 16 + lq) * 64;
                bf16x8 b0 = *(const bf16x8*)(kb + kf0);
                bf16x8 b1 = *(const bf16x8*)(kb + kf1);
                acc[jt] = __builtin_amdgcn_mfma_f32_16x16x32_bf16(aq0, b0, acc[jt], 0, 0, 0);
                acc[jt] = __builtin_amdgcn_mfma_f32_16x16x32_bf16(aq1, b1, acc[jt], 0, 0, 0);
            }
            #pragma unroll
            for (int r = 0; r < 4; ++r) {
                float e[4];
                #pragma unroll
                for (int jt = 0; jt < 4; ++jt) {
                    unsigned msk = (bits[jt][r] >> (kt0 + tt)) & 1u;
                    float ev = exp2f(acc[jt][r]);
                    e[jt] = msk ? 0.f : ev;
                }
                lsum[r] += (e[0] + e[1]) + (e[2] + e[3]);
            }
        }

        if (more) {
            #pragma unroll
            for (int tt = 0; tt < 2; ++tt)
                #pragma unroll
                for (int jt = 0; jt < 4; ++jt)
                    #pragma unroll
                    for (int r = 0; r < 4; ++r)
                        bits[jt][r] |= (mn[tt][jt][r] ? 1u : 0u) << (kt0 + 2 + tt);
        }
        __syncthreads();
    }

    // add-only butterfly; full 16-wide xor leaves the total in ALL lanes
    float myIL[4];
    #pragma unroll
    for (int r = 0; r < 4; ++r) {
        float li = lsum[r];
        #pragma unroll
        for (int off = 1; off < 16; off <<= 1)
            li += __shfl_xor(li, off);
        myIL[r] = (li > 0.f) ? (1.f / li) : 0.f;
    }

    // ---- pass-2 prologue: issue K(0),K(1) and V(0),V(1) into pair 0 --------
    #pragma unroll
    for (int tt = 0; tt < 2; ++tt) {
        gload16((const unsigned char*)(Kh + (size_t)tt * 4096) + tid * 16,
                smem + tt * 8192 + tid * 16);
        gload16((const unsigned char*)(Vh + (size_t)tt * 4096) + tid * 16,
                smem + 32768 + tt * 8192 + tid * 16);
    }
    __syncthreads();

    // ================= pass 2: 16 steps x 2 tiles ===========================
    f32x4 ctxa[4];
    #pragma unroll
    for (int dt = 0; dt < 4; ++dt) ctxa[dt] = (f32x4){0.f, 0.f, 0.f, 0.f};

    unsigned short* const sPw = sPB + w * 1024;
    float* const Abase = Ah + (size_t)(q0 + w * 16) * S_LEN;

    for (int s = 0; s < 16; ++s) {
        const int kt0 = 2 * s;
        unsigned char* curK = smem + (s & 1) * 16384;
        unsigned char* nxtK = smem + ((s & 1) ^ 1) * 16384;
        unsigned char* curV = smem + 32768 + (s & 1) * 16384;
        unsigned char* nxtV = smem + 32768 + ((s & 1) ^ 1) * 16384;
        const bool more = (s + 1 < 16);

        if (more) {
            #pragma unroll
            for (int tt = 0; tt < 2; ++tt) {
                gload16((const unsigned char*)(Kh + (size_t)(kt0 + 2 + tt) * 4096) + tid * 16,
                        nxtK + tt * 8192 + tid * 16);
                gload16((const unsigned char*)(Vh + (size_t)(kt0 + 2 + tt) * 4096) + tid * 16,
                        nxtV + tt * 8192 + tid * 16);
            }
        }
        __builtin_amdgcn_sched_barrier(0);

        #pragma unroll
        for (int tt = 0; tt < 2; ++tt) {
            const int kt = kt0 + tt;
            const unsigned short* kbuf = (const unsigned short*)(curK + tt * 8192);

            f32x4 acc[4];
            #pragma unroll
            for (int jt = 0; jt < 4; ++jt) {
                acc[jt] = (f32x4){0.f, 0.f, 0.f, 0.f};
                const unsigned short* kb = kbuf + (jt * 16 + lq) * 64;
                bf16x8 b0 = *(const bf16x8*)(kb + kf0);
                bf16x8 b1 = *(const bf16x8*)(kb + kf1);
                acc[jt] = __builtin_amdgcn_mfma_f32_16x16x32_bf16(aq0, b0, acc[jt], 0, 0, 0);
                acc[jt] = __builtin_amdgcn_mfma_f32_16x16x32_bf16(aq1, b1, acc[jt], 0, 0, 0);
            }

            // wave-local: prior ds_reads of sPw done before overwrite
            asm volatile("s_waitcnt lgkmcnt(0)" ::: "memory");

            // P -> per-wave swizzled LDS tile (bf16)
            #pragma unroll
            for (int jt = 0; jt < 4; ++jt)
                #pragma unroll
                for (int r = 0; r < 4; ++r) {
                    bool msk = (bits[jt][r] >> kt) & 1u;
                    float p = exp2f(acc[jt][r]) * myIL[r];
                    p = msk ? 0.f : p;
                    int row = h * 4 + r;
                    sPw[row * 64 + ((((jt << 1) | (lq >> 3)) ^ (row & 7)) << 3) + l7] = f2bf(p);
                }
            asm volatile("s_waitcnt lgkmcnt(0)" ::: "memory");
            __builtin_amdgcn_sched_barrier(0);

            // coalesced attn write from sPw
            float* Aw = Abase + kt * 64;
            #pragma unroll
            for (int it = 0; it < 4; ++it) {
                int row = it * 4 + h;
                us4 pb = *(const us4*)(&sPw[row * 64 + (((lq >> 1) ^ (row & 7)) << 3) + (lq & 1) * 4]);
                float4 pf = make_float4(bf2f(pb.x), bf2f(pb.y), bf2f(pb.z), bf2f(pb.w));
                *(float4*)(Aw + (size_t)row * S_LEN + lq * 4) = pf;
            }

            // PV: P from LDS, V from staged LDS quad
            bf16x8 pa0 = *(const bf16x8*)(&sPw[lq * 64 + ((h ^ l7) << 3)]);
            bf16x8 pa1 = *(const bf16x8*)(&sPw[lq * 64 + (((4 + h) ^ l7) << 3)]);
            const unsigned short* vbuf = (const unsigned short*)(curV + tt * 8192);
            #pragma unroll
            for (int dt = 0; dt < 4; ++dt) {
                const unsigned short* vb = vbuf + (dt * 16 + lq) * 64;
                bf16x8 v0 = *(const bf16x8*)(vb + kf0);
                bf16x8 v1 = *(const bf16x8*)(vb + kf1);
                ctxa[dt] = __builtin_amdgcn_mfma_f32_16x16x32_bf16(pa0, v0, ctxa[dt], 0, 0, 0);
                ctxa[dt] = __builtin_amdgcn_mfma_f32_16x16x32_bf16(pa1, v1, ctxa[dt], 0, 0, 0);
            }
        }
        __syncthreads();
    }

    float* Crow = Ch + (size_t)(q0 + w * 16 + h * 4) * D_DIM;
    #pragma unroll
    for (int dt = 0; dt < 4; ++dt)
        #pragma unroll
        for (int r = 0; r < 4; ++r)
            Crow[(size_t)r * D_DIM + dt * 16 + lq] = ctxa[dt][r];
}

extern "C" void kernel_launch(void* const* d_in, const int* in_sizes, int n_in,
                              void* d_out, int out_size, void* d_ws, size_t ws_size,
                              hipStream_t stream)
{
    const float* Q = (const float*)d_in[0];
    const float* K = (const float*)d_in[1];
    const float* V = (const float*)d_in[2];
    const int*   M = (const int*)d_in[3];

    float* ctx  = (float*)d_out;
    float* attn = ctx + (size_t)2 * 16 * S_LEN * D_DIM;

    const size_t imgElems = (size_t)32 * NKT * 4096;
    if (ws_size < 2 * imgElems * sizeof(unsigned short)) return; // need 16 MB
    unsigned short* Kimg = (unsigned short*)d_ws;
    unsigned short* Vimg = Kimg + imgElems;

    sdpa_prep<<<dim3(1024), 256, 0, stream>>>(K, V, Kimg, Vimg);
    sdpa_main<<<dim3(512), 512, 0, stream>>>(Q, M, Kimg, Vimg, ctx, attn);
}